// Round 5
// baseline (336.457 us; speedup 1.0000x reference)
//
#include <hip/hip_runtime.h>
#include <hip/hip_bf16.h>

#define BATCH 128
#define TLEN  65536
#define EDIM  512
#define SMAX  512

typedef __attribute__((ext_vector_type(8))) short   bf16x8;
typedef __attribute__((ext_vector_type(4))) float   floatx4;
typedef __attribute__((ext_vector_type(8))) ushort  ushort8;

__device__ __forceinline__ ushort f2bf(float f) {
  __hip_bfloat16 h = __float2bfloat16(f);  // RNE
  return *reinterpret_cast<ushort*>(&h);
}

// pack two float4 (8 consecutive k-elems) into one bf16x8 MFMA fragment
__device__ __forceinline__ bf16x8 cvt_frag(float4 lo, float4 hi) {
  ushort8 u;
  u[0] = f2bf(lo.x); u[1] = f2bf(lo.y); u[2] = f2bf(lo.z); u[3] = f2bf(lo.w);
  u[4] = f2bf(hi.x); u[5] = f2bf(hi.y); u[6] = f2bf(hi.z); u[7] = f2bf(hi.w);
  return __builtin_bit_cast(bf16x8, u);
}

// ---------------------------------------------------------------------------
// mask popcount stage A: part[b*8+c] = popcount of 8192-int chunk c of row b
// ---------------------------------------------------------------------------
__global__ __launch_bounds__(256) void mask_partial_kernel(
    const int* __restrict__ mask, int* __restrict__ part) {
  const int b = blockIdx.x, c = blockIdx.y, t = threadIdx.x;
  const int4* row = (const int4*)(mask + (size_t)b * TLEN + (size_t)c * 8192);
  int s = 0;
  #pragma unroll
  for (int i = 0; i < 8; ++i) {
    int4 v = row[t + i * 256];
    s += (v.x != 0) + (v.y != 0) + (v.z != 0) + (v.w != 0);
  }
  #pragma unroll
  for (int off = 32; off > 0; off >>= 1) s += __shfl_down(s, off);
  __shared__ int partial[4];
  if ((t & 63) == 0) partial[t >> 6] = s;
  __syncthreads();
  if (t == 0)
    part[b * 8 + c] = partial[0] + partial[1] + partial[2] + partial[3];
}

// ---------------------------------------------------------------------------
// mask stage B: n_valid[b] + padding_mask output
// ---------------------------------------------------------------------------
__global__ __launch_bounds__(256) void mask_final_kernel(
    const int* __restrict__ part, const int* __restrict__ branch_idx,
    int* __restrict__ n_valid, float* __restrict__ out_mask) {
  const int b = blockIdx.x, t = threadIdx.x;
  __shared__ int nv_sh;
  if (t == 0) {
    int len = 0;
    #pragma unroll
    for (int i = 0; i < 8; ++i) len += part[b * 8 + i];
    int w = 128 << branch_idx[b];
    int nv = len / w;
    n_valid[b] = nv;
    nv_sh = nv;
  }
  __syncthreads();
  const int nv = nv_sh;
  out_mask[(size_t)b * SMAX + t]       = (t < nv)       ? 1.0f : 0.0f;
  out_mask[(size_t)b * SMAX + 256 + t] = (256 + t < nv) ? 1.0f : 0.0f;
}

// ---------------------------------------------------------------------------
// Direct-from-global MFMA GEMM: no LDS, no barriers, no DMA.
// Per block: 128(s) x 128(e) tile, 4 waves = 2x2 of 64x64.
// A-frag rows (signal patches) and B-frag rows (W) are loaded straight from
// row-major f32 global as 2x float4 per fragment, converted in-reg to bf16.
// A streams from HBM (reuse via L2 across the 4 e-tile blocks + wave pairs);
// W (<=1 MB f32 per branch) is L2-resident.
// ---------------------------------------------------------------------------
template <int W>
__device__ __forceinline__ void gemm_direct_body(
    const float* __restrict__ sigb, const float* __restrict__ Wp,
    const float* __restrict__ bp, float* __restrict__ outb,
    int nv, int s0, int e0, int t) {
  constexpr int ITERS = W / 32;
  const int wave = t >> 6, lane = t & 63;
  const int lane16 = lane & 15, quad = lane >> 4;
  const int ws_ = (wave >> 1) * 64, we_ = (wave & 1) * 64;

  // per-lane row base pointers at k-offset quad*8
  const float* ap[4];
  const float* bpr[4];
  #pragma unroll
  for (int i = 0; i < 4; ++i)
    ap[i] = sigb + (size_t)(s0 + ws_ + i * 16 + lane16) * W + quad * 8;
  #pragma unroll
  for (int j = 0; j < 4; ++j)
    bpr[j] = Wp + (size_t)(e0 + we_ + j * 16 + lane16) * W + quad * 8;

  floatx4 acc[4][4];
  #pragma unroll
  for (int i = 0; i < 4; ++i)
    #pragma unroll
    for (int j = 0; j < 4; ++j) acc[i][j] = (floatx4)(0.f);

  #pragma unroll
  for (int k = 0; k < ITERS; ++k) {
    // issue all 16 loads for this k-step, then convert, then MFMA;
    // no barriers -> compiler/scheduler freely overlaps across iterations.
    float4 al[4][2], bl[4][2];
    #pragma unroll
    for (int i = 0; i < 4; ++i) {
      al[i][0] = *(const float4*)(ap[i] + k * 32);
      al[i][1] = *(const float4*)(ap[i] + k * 32 + 4);
    }
    #pragma unroll
    for (int j = 0; j < 4; ++j) {
      bl[j][0] = *(const float4*)(bpr[j] + k * 32);
      bl[j][1] = *(const float4*)(bpr[j] + k * 32 + 4);
    }
    bf16x8 af[4], bfr[4];
    #pragma unroll
    for (int i = 0; i < 4; ++i) af[i] = cvt_frag(al[i][0], al[i][1]);
    #pragma unroll
    for (int j = 0; j < 4; ++j) bfr[j] = cvt_frag(bl[j][0], bl[j][1]);
    #pragma unroll
    for (int i = 0; i < 4; ++i)
      #pragma unroll
      for (int j = 0; j < 4; ++j)
        acc[i][j] = __builtin_amdgcn_mfma_f32_16x16x32_bf16(af[i], bfr[j], acc[i][j], 0, 0, 0);
  }

  // epilogue: bias + row masking (exact zeros for rows >= nv)
  float bval[4];
  #pragma unroll
  for (int j = 0; j < 4; ++j) bval[j] = bp[e0 + we_ + j * 16 + lane16];
  #pragma unroll
  for (int i = 0; i < 4; ++i) {
    #pragma unroll
    for (int rr = 0; rr < 4; ++rr) {
      const int s_row = s0 + ws_ + i * 16 + quad * 4 + rr;
      const bool valid = s_row < nv;
      float* op = outb + (size_t)s_row * EDIM + e0 + we_ + lane16;
      #pragma unroll
      for (int j = 0; j < 4; ++j)
        op[j * 16] = valid ? (acc[i][j][rr] + bval[j]) : 0.f;
    }
  }
}

__global__ __launch_bounds__(256) void gemm_kernel(
    const float* __restrict__ signal, const int* __restrict__ branch_idx,
    const int* __restrict__ n_valid_arr,
    const float* __restrict__ W0, const float* __restrict__ bias0,
    const float* __restrict__ W1, const float* __restrict__ bias1,
    const float* __restrict__ W2, const float* __restrict__ bias2,
    float* __restrict__ out) {
  const int et = blockIdx.x, st = blockIdx.y, b = blockIdx.z;
  const int t = threadIdx.x;
  const int s0 = st * 128, e0 = et * 128;
  const int bi = branch_idx[b];
  const int S_b = 512 >> bi;   // rows this branch actually produces
  float* outb = out + (size_t)b * SMAX * EDIM;

  if (s0 >= S_b) {  // pure pad tile: zero-fill (harness poisons d_out)
    const float4 z = make_float4(0.f, 0.f, 0.f, 0.f);
    #pragma unroll
    for (int i = 0; i < 16; ++i) {
      int idx = t + i * 256;
      int r = idx >> 5, c = idx & 31;
      *(float4*)(outb + (size_t)(s0 + r) * EDIM + e0 + c * 4) = z;
    }
    return;
  }
  // computing tile: s0 < S_b and both are multiples of 128 -> all 128 rows
  // are < S_b, so every signal read is within this sample's TLEN floats.

  const int nv = n_valid_arr[b];
  const float* sigb = signal + (size_t)b * TLEN;
  switch (bi) {
    case 0:  gemm_direct_body<128>(sigb, W0, bias0, outb, nv, s0, e0, t); break;
    case 1:  gemm_direct_body<256>(sigb, W1, bias1, outb, nv, s0, e0, t); break;
    default: gemm_direct_body<512>(sigb, W2, bias2, outb, nv, s0, e0, t); break;
  }
}

extern "C" void kernel_launch(void* const* d_in, const int* in_sizes, int n_in,
                              void* d_out, int out_size, void* d_ws, size_t ws_size,
                              hipStream_t stream) {
  const float* signal = (const float*)d_in[0];
  const int*   mask   = (const int*)d_in[1];
  const int*   bidx   = (const int*)d_in[2];
  const float* W0 = (const float*)d_in[3];
  const float* b0 = (const float*)d_in[4];
  const float* W1 = (const float*)d_in[5];
  const float* b1 = (const float*)d_in[6];
  const float* W2 = (const float*)d_in[7];
  const float* b2 = (const float*)d_in[8];

  float* out_tokens = (float*)d_out;
  float* out_mask   = (float*)d_out + (size_t)BATCH * SMAX * EDIM;
  int*   n_valid    = (int*)d_ws;             // 128 ints
  int*   part       = (int*)d_ws + 128;       // 1024 ints

  mask_partial_kernel<<<dim3(BATCH, 8), dim3(256), 0, stream>>>(mask, part);
  mask_final_kernel<<<dim3(BATCH), dim3(256), 0, stream>>>(part, bidx, n_valid, out_mask);
  gemm_kernel<<<dim3(4, 4, BATCH), dim3(256), 0, stream>>>(
      signal, bidx, n_valid, W0, b0, W1, b1, W2, b2, out_tokens);
}

// Round 6
// 249.416 us; speedup vs baseline: 1.3490x; 1.3490x over previous
//
#include <hip/hip_runtime.h>
#include <hip/hip_bf16.h>

#define BATCH 128
#define TLEN  65536
#define EDIM  512
#define SMAX  512

typedef __attribute__((ext_vector_type(8))) short   bf16x8;
typedef __attribute__((ext_vector_type(4))) float   floatx4;
typedef __attribute__((ext_vector_type(8))) ushort  ushort8;

__device__ __forceinline__ ushort f2bf(float f) {
  __hip_bfloat16 h = __float2bfloat16(f);  // RNE
  return *reinterpret_cast<ushort*>(&h);
}

__device__ __forceinline__ void cvt16(ushort* dst, float4 a, float4 b,
                                      float4 c, float4 d) {
  ushort8 p0, p1;
  p0[0]=f2bf(a.x); p0[1]=f2bf(a.y); p0[2]=f2bf(a.z); p0[3]=f2bf(a.w);
  p0[4]=f2bf(b.x); p0[5]=f2bf(b.y); p0[6]=f2bf(b.z); p0[7]=f2bf(b.w);
  p1[0]=f2bf(c.x); p1[1]=f2bf(c.y); p1[2]=f2bf(c.z); p1[3]=f2bf(c.w);
  p1[4]=f2bf(d.x); p1[5]=f2bf(d.y); p1[6]=f2bf(d.z); p1[7]=f2bf(d.w);
  *(ushort8*)dst = p0; *(ushort8*)(dst + 8) = p1;
}

// pack two float4 (8 consecutive k-elems) into one bf16x8 MFMA fragment
__device__ __forceinline__ bf16x8 cvt_frag(float4 lo, float4 hi) {
  ushort8 u;
  u[0] = f2bf(lo.x); u[1] = f2bf(lo.y); u[2] = f2bf(lo.z); u[3] = f2bf(lo.w);
  u[4] = f2bf(hi.x); u[5] = f2bf(hi.y); u[6] = f2bf(hi.z); u[7] = f2bf(hi.w);
  return __builtin_bit_cast(bf16x8, u);
}

__device__ __forceinline__ void gl_lds16_f(const float* g, float* l) {
  __builtin_amdgcn_global_load_lds(
      (const __attribute__((address_space(1))) void*)g,
      (__attribute__((address_space(3))) void*)l, 16, 0, 0);
}
__device__ __forceinline__ void gl_lds16_u(const ushort* g, ushort* l) {
  __builtin_amdgcn_global_load_lds(
      (const __attribute__((address_space(1))) void*)g,
      (__attribute__((address_space(3))) void*)l, 16, 0, 0);
}

// ---------------------------------------------------------------------------
// mask popcount stage A: part[b*8+c] = popcount of 8192-int chunk c of row b
// ---------------------------------------------------------------------------
__global__ __launch_bounds__(256) void mask_partial_kernel(
    const int* __restrict__ mask, int* __restrict__ part) {
  const int b = blockIdx.x, c = blockIdx.y, t = threadIdx.x;
  const int4* row = (const int4*)(mask + (size_t)b * TLEN + (size_t)c * 8192);
  int s = 0;
  #pragma unroll
  for (int i = 0; i < 8; ++i) {
    int4 v = row[t + i * 256];
    s += (v.x != 0) + (v.y != 0) + (v.z != 0) + (v.w != 0);
  }
  #pragma unroll
  for (int off = 32; off > 0; off >>= 1) s += __shfl_down(s, off);
  __shared__ int partial[4];
  if ((t & 63) == 0) partial[t >> 6] = s;
  __syncthreads();
  if (t == 0)
    part[b * 8 + c] = partial[0] + partial[1] + partial[2] + partial[3];
}

// ---------------------------------------------------------------------------
// mask stage B: n_valid[b] + padding_mask output
// ---------------------------------------------------------------------------
__global__ __launch_bounds__(256) void mask_final_kernel(
    const int* __restrict__ part, const int* __restrict__ branch_idx,
    int* __restrict__ n_valid, float* __restrict__ out_mask) {
  const int b = blockIdx.x, t = threadIdx.x;
  __shared__ int nv_sh;
  if (t == 0) {
    int len = 0;
    #pragma unroll
    for (int i = 0; i < 8; ++i) len += part[b * 8 + i];
    int w = 128 << branch_idx[b];
    int nv = len / w;
    n_valid[b] = nv;
    nv_sh = nv;
  }
  __syncthreads();
  const int nv = nv_sh;
  out_mask[(size_t)b * SMAX + t]       = (t < nv)       ? 1.0f : 0.0f;
  out_mask[(size_t)b * SMAX + 256 + t] = (256 + t < nv) ? 1.0f : 0.0f;
}

// ---------------------------------------------------------------------------
// f32 -> bf16 pre-convert of the three weight matrices only (0.92 MB total).
// ---------------------------------------------------------------------------
#define W0N   (EDIM * 128)
#define W1N   (EDIM * 256)
#define W2N   (EDIM * 512)
#define WTOT  (W0N + W1N + W2N)   // 458752 = 4096 * 112

__global__ __launch_bounds__(256) void cvtw_kernel(
    const float* __restrict__ W0, const float* __restrict__ W1,
    const float* __restrict__ W2, ushort* __restrict__ dst) {
  const size_t i = ((size_t)blockIdx.x * 256 + threadIdx.x) * 16;
  const float* src;
  if (i < W0N)             src = W0 + i;
  else if (i < W0N + W1N)  src = W1 + (i - W0N);
  else                     src = W2 + (i - W0N - W1N);
  const float4* s4 = (const float4*)src;
  cvt16(dst + i, s4[0], s4[1], s4[2], s4[3]);
}

// ---------------------------------------------------------------------------
// Main GEMM. 128x128 tile, 4 waves (2x2 of 64x64), BK=32, 16x16x32 bf16 MFMA.
// A (signal) staged as *f32* straight from the input via global_load_lds
// (16 KB/stage, double-buffered), converted to bf16 per-fragment in regs.
// B (weights) staged as bf16 from the pre-converted ws copy (8 KB/stage).
//
// A LDS layout: row r (128B = 8 chunks of 16B); chunk position p holds
// logical k-chunk kc = p ^ (r&7). DMA staging is lane-contiguous in flat
// chunk index; fragment reads are spread evenly over all 32 banks.
// B LDS layout (R4-proven): row r (64B = 4 chunks); position p holds
// kc = p ^ (r&3).
// ---------------------------------------------------------------------------
template <int W>
__device__ __forceinline__ void gemm_body(
    const float* __restrict__ sigb, const ushort* __restrict__ Wp,
    const float* __restrict__ bp, float* __restrict__ outb,
    int nv, int s0, int e0, int t, float* Af, ushort* Bu) {
  constexpr int ITERS = W / 32;
  const int wave = t >> 6, lane = t & 63;
  const int lane16 = lane & 15, quad = lane >> 4;
  const int ws_ = (wave >> 1) * 64, we_ = (wave & 1) * 64;

  // ---- A staging map: 1024 chunks/stage, 4 per thread ----
  const float* ag[4];
  #pragma unroll
  for (int i = 0; i < 4; ++i) {
    const int c = t + i * 256;
    const int row = c >> 3, kc = (c & 7) ^ (row & 7);
    ag[i] = sigb + (size_t)(s0 + row) * W + kc * 4;
  }
  float* al[4];  // wave-uniform dest bases (HW adds lane*16B)
  #pragma unroll
  for (int i = 0; i < 4; ++i) al[i] = Af + (i * 256 + wave * 64) * 4;

  // ---- B staging map: 512 chunks/stage, 2 per thread ----
  const ushort* bg[2];
  #pragma unroll
  for (int i = 0; i < 2; ++i) {
    const int c = t + i * 256;
    const int row = c >> 2, kc = (c & 3) ^ (row & 3);
    bg[i] = Wp + (size_t)(e0 + row) * W + kc * 8;
  }
  ushort* bl[2];
  #pragma unroll
  for (int i = 0; i < 2; ++i) bl[i] = Bu + (i * 256 + wave * 64) * 8;

  floatx4 acc[4][4];
  #pragma unroll
  for (int i = 0; i < 4; ++i)
    #pragma unroll
    for (int j = 0; j < 4; ++j) acc[i][j] = (floatx4)(0.f);

  // prologue: stage 0 -> buffer 0
  #pragma unroll
  for (int i = 0; i < 4; ++i) gl_lds16_f(ag[i], al[i]);
  #pragma unroll
  for (int i = 0; i < 2; ++i) gl_lds16_u(bg[i], bl[i]);
  __syncthreads();

  // lane-constant swizzled read positions
  const int pa0 = ((quad * 2) ^ (lane16 & 7)) * 4;      // floats
  const int pa1 = ((quad * 2 + 1) ^ (lane16 & 7)) * 4;  // floats
  const int pb  = (quad ^ (lane16 & 3)) * 8;            // ushorts

  #pragma unroll
  for (int k = 0; k < ITERS; ++k) {
    if (k + 1 < ITERS) {  // issue next stage into the other buffer
      const int ko = (k + 1) * 32;
      const int pa = ((k + 1) & 1) * 4096;  // floats
      const int pbuf = ((k + 1) & 1) * 4096;  // ushorts
      #pragma unroll
      for (int i = 0; i < 4; ++i) gl_lds16_f(ag[i] + ko, al[i] + pa);
      #pragma unroll
      for (int i = 0; i < 2; ++i) gl_lds16_u(bg[i] + ko, bl[i] + pbuf);
    }
    const float* A = Af + (k & 1) * 4096;
    const ushort* B = Bu + (k & 1) * 4096;
    bf16x8 af[4], bfr[4];
    #pragma unroll
    for (int i = 0; i < 4; ++i) {
      const int ra = ws_ + i * 16 + lane16;
      float4 a0 = *(const float4*)(A + ra * 32 + pa0);
      float4 a1 = *(const float4*)(A + ra * 32 + pa1);
      af[i] = cvt_frag(a0, a1);
    }
    #pragma unroll
    for (int j = 0; j < 4; ++j)
      bfr[j] = *(const bf16x8*)&B[(we_ + j * 16 + lane16) * 32 + pb];
    #pragma unroll
    for (int i = 0; i < 4; ++i)
      #pragma unroll
      for (int j = 0; j < 4; ++j)
        acc[i][j] = __builtin_amdgcn_mfma_f32_16x16x32_bf16(af[i], bfr[j], acc[i][j], 0, 0, 0);
    __syncthreads();
  }

  // epilogue: bias + row masking (exact zeros for rows >= nv)
  float bval[4];
  #pragma unroll
  for (int j = 0; j < 4; ++j) bval[j] = bp[e0 + we_ + j * 16 + lane16];
  #pragma unroll
  for (int i = 0; i < 4; ++i) {
    #pragma unroll
    for (int rr = 0; rr < 4; ++rr) {
      const int s_row = s0 + ws_ + i * 16 + quad * 4 + rr;
      const bool valid = s_row < nv;
      float* op = outb + (size_t)s_row * EDIM + e0 + we_ + lane16;
      #pragma unroll
      for (int j = 0; j < 4; ++j)
        op[j * 16] = valid ? (acc[i][j][rr] + bval[j]) : 0.f;
    }
  }
}

__global__ __launch_bounds__(256) void gemm_kernel(
    const float* __restrict__ signal, const int* __restrict__ branch_idx,
    const int* __restrict__ n_valid_arr, const ushort* __restrict__ wbf,
    const float* __restrict__ bias0, const float* __restrict__ bias1,
    const float* __restrict__ bias2, float* __restrict__ out) {
  const int et = blockIdx.x, st = blockIdx.y, b = blockIdx.z;
  const int t = threadIdx.x;
  const int s0 = st * 128, e0 = et * 128;
  const int bi = branch_idx[b];
  const int S_b = 512 >> bi;
  float* outb = out + (size_t)b * SMAX * EDIM;

  if (s0 >= S_b) {  // pure pad tile: zero-fill (harness poisons d_out)
    const float4 z = make_float4(0.f, 0.f, 0.f, 0.f);
    #pragma unroll
    for (int i = 0; i < 16; ++i) {
      int idx = t + i * 256;
      int r = idx >> 5, c = idx & 31;
      *(float4*)(outb + (size_t)(s0 + r) * EDIM + e0 + c * 4) = z;
    }
    return;
  }

  __shared__ __align__(16) float  Af[2 * 4096];   // 32 KB (A, f32)
  __shared__ __align__(16) ushort Bu[2 * 4096];   // 16 KB (B, bf16)
  const int nv = n_valid_arr[b];
  const float* sigb = signal + (size_t)b * TLEN;
  switch (bi) {
    case 0:
      gemm_body<128>(sigb, wbf, bias0, outb, nv, s0, e0, t, Af, Bu); break;
    case 1:
      gemm_body<256>(sigb, wbf + W0N, bias1, outb, nv, s0, e0, t, Af, Bu); break;
    default:
      gemm_body<512>(sigb, wbf + W0N + W1N, bias2, outb, nv, s0, e0, t, Af, Bu); break;
  }
}

// ---------------------------------------------------------------------------
// Fallback (ws too small): R3-style inline-cvt LDS GEMM, known-correct.
// ---------------------------------------------------------------------------
#define LDS_STRIDE 40
#define BUFSZ (128 * LDS_STRIDE)

template <int W>
__device__ __forceinline__ void gemm_fb_body(
    const float* __restrict__ sigb, const float* __restrict__ Wp,
    const float* __restrict__ bp, float* __restrict__ outb,
    int nv, int s0, int e0, int t, ushort* Ab, ushort* Bb) {
  constexpr int ITERS = W / 32;
  const int wave = t >> 6, lane = t & 63;
  const int lane16 = lane & 15, quad = lane >> 4;
  const int ws_ = (wave >> 1) * 64, we_ = (wave & 1) * 64;
  const int r = t >> 1, h = t & 1;
  const float* asrc = sigb + (size_t)(s0 + r) * W + h * 16;
  const float* bsrc = Wp + (size_t)(e0 + r) * W + h * 16;
  {
    const float4* a4 = (const float4*)asrc;
    const float4* b4 = (const float4*)bsrc;
    cvt16(Ab + r * LDS_STRIDE + h * 16, a4[0], a4[1], a4[2], a4[3]);
    cvt16(Bb + r * LDS_STRIDE + h * 16, b4[0], b4[1], b4[2], b4[3]);
  }
  __syncthreads();
  floatx4 acc[4][4];
  #pragma unroll
  for (int i = 0; i < 4; ++i)
    #pragma unroll
    for (int j = 0; j < 4; ++j) acc[i][j] = (floatx4)(0.f);
  #pragma unroll
  for (int k = 0; k < ITERS; ++k) {
    const ushort* curA = Ab + (k & 1) * BUFSZ;
    const ushort* curB = Bb + (k & 1) * BUFSZ;
    float4 av0, av1, av2, av3, bv0, bv1, bv2, bv3;
    if (k + 1 < ITERS) {
      const float4* a4 = (const float4*)(asrc + (k + 1) * 32);
      const float4* b4 = (const float4*)(bsrc + (k + 1) * 32);
      av0 = a4[0]; av1 = a4[1]; av2 = a4[2]; av3 = a4[3];
      bv0 = b4[0]; bv1 = b4[1]; bv2 = b4[2]; bv3 = b4[3];
    }
    bf16x8 af[4], bfr[4];
    #pragma unroll
    for (int i = 0; i < 4; ++i)
      af[i] = *(const bf16x8*)&curA[(ws_ + i * 16 + lane16) * LDS_STRIDE + quad * 8];
    #pragma unroll
    for (int j = 0; j < 4; ++j)
      bfr[j] = *(const bf16x8*)&curB[(we_ + j * 16 + lane16) * LDS_STRIDE + quad * 8];
    #pragma unroll
    for (int i = 0; i < 4; ++i)
      #pragma unroll
      for (int j = 0; j < 4; ++j)
        acc[i][j] = __builtin_amdgcn_mfma_f32_16x16x32_bf16(af[i], bfr[j], acc[i][j], 0, 0, 0);
    if (k + 1 < ITERS) {
      cvt16(Ab + ((k + 1) & 1) * BUFSZ + r * LDS_STRIDE + h * 16, av0, av1, av2, av3);
      cvt16(Bb + ((k + 1) & 1) * BUFSZ + r * LDS_STRIDE + h * 16, bv0, bv1, bv2, bv3);
      __syncthreads();
    }
  }
  float bval[4];
  #pragma unroll
  for (int j = 0; j < 4; ++j) bval[j] = bp[e0 + we_ + j * 16 + lane16];
  #pragma unroll
  for (int i = 0; i < 4; ++i) {
    #pragma unroll
    for (int rr = 0; rr < 4; ++rr) {
      const int s_row = s0 + ws_ + i * 16 + quad * 4 + rr;
      const bool valid = s_row < nv;
      float* op = outb + (size_t)s_row * EDIM + e0 + we_ + lane16;
      #pragma unroll
      for (int j = 0; j < 4; ++j)
        op[j * 16] = valid ? (acc[i][j][rr] + bval[j]) : 0.f;
    }
  }
}

__global__ __launch_bounds__(256) void gemm_fb_kernel(
    const float* __restrict__ signal, const int* __restrict__ branch_idx,
    const int* __restrict__ n_valid_arr,
    const float* __restrict__ W0, const float* __restrict__ bias0,
    const float* __restrict__ W1, const float* __restrict__ bias1,
    const float* __restrict__ W2, const float* __restrict__ bias2,
    float* __restrict__ out) {
  const int et = blockIdx.x, st = blockIdx.y, b = blockIdx.z;
  const int t = threadIdx.x;
  const int s0 = st * 128, e0 = et * 128;
  const int bi = branch_idx[b];
  const int S_b = 512 >> bi;
  float* outb = out + (size_t)b * SMAX * EDIM;
  if (s0 >= S_b) {
    const float4 z = make_float4(0.f, 0.f, 0.f, 0.f);
    #pragma unroll
    for (int i = 0; i < 16; ++i) {
      int idx = t + i * 256;
      int r = idx >> 5, c = idx & 31;
      *(float4*)(outb + (size_t)(s0 + r) * EDIM + e0 + c * 4) = z;
    }
    return;
  }
  __shared__ __align__(16) ushort Ab[2 * BUFSZ];
  __shared__ __align__(16) ushort Bb[2 * BUFSZ];
  const int nv = n_valid_arr[b];
  const float* sigb = signal + (size_t)b * TLEN;
  switch (bi) {
    case 0:  gemm_fb_body<128>(sigb, W0, bias0, outb, nv, s0, e0, t, Ab, Bb); break;
    case 1:  gemm_fb_body<256>(sigb, W1, bias1, outb, nv, s0, e0, t, Ab, Bb); break;
    default: gemm_fb_body<512>(sigb, W2, bias2, outb, nv, s0, e0, t, Ab, Bb); break;
  }
}

extern "C" void kernel_launch(void* const* d_in, const int* in_sizes, int n_in,
                              void* d_out, int out_size, void* d_ws, size_t ws_size,
                              hipStream_t stream) {
  const float* signal = (const float*)d_in[0];
  const int*   mask   = (const int*)d_in[1];
  const int*   bidx   = (const int*)d_in[2];
  const float* W0 = (const float*)d_in[3];
  const float* b0 = (const float*)d_in[4];
  const float* W1 = (const float*)d_in[5];
  const float* b1 = (const float*)d_in[6];
  const float* W2 = (const float*)d_in[7];
  const float* b2 = (const float*)d_in[8];

  float* out_tokens = (float*)d_out;
  float* out_mask   = (float*)d_out + (size_t)BATCH * SMAX * EDIM;
  int*   n_valid    = (int*)d_ws;             // 128 ints
  int*   part       = (int*)d_ws + 128;       // 1024 ints

  const size_t need = 8192 + (size_t)WTOT * 2;
  if (ws_size >= need) {
    ushort* wbf = (ushort*)((char*)d_ws + 8192);
    cvtw_kernel<<<dim3(WTOT / 4096), dim3(256), 0, stream>>>(W0, W1, W2, wbf);
    mask_partial_kernel<<<dim3(BATCH, 8), dim3(256), 0, stream>>>(mask, part);
    mask_final_kernel<<<dim3(BATCH), dim3(256), 0, stream>>>(part, bidx, n_valid, out_mask);
    gemm_kernel<<<dim3(4, 4, BATCH), dim3(256), 0, stream>>>(
        signal, bidx, n_valid, wbf, b0, b1, b2, out_tokens);
  } else {
    mask_partial_kernel<<<dim3(BATCH, 8), dim3(256), 0, stream>>>(mask, part);
    mask_final_kernel<<<dim3(BATCH), dim3(256), 0, stream>>>(part, bidx, n_valid, out_mask);
    gemm_fb_kernel<<<dim3(4, 4, BATCH), dim3(256), 0, stream>>>(
        signal, bidx, n_valid, W0, b0, W1, b1, W2, b2, out_tokens);
  }
}